// Round 4
// baseline (183.954 us; speedup 1.0000x reference)
//
#include <hip/hip_runtime.h>
#include <hip/hip_bf16.h>

#define P_TOT 32768   // H*W
#define O_QKV 768

using f32x4   = float  __attribute__((ext_vector_type(4)));
using bf16x8  = __bf16 __attribute__((ext_vector_type(8)));
using ushort8 = unsigned short __attribute__((ext_vector_type(8)));

typedef __attribute__((address_space(1))) void* gptr_t;
typedef __attribute__((address_space(3))) void* sptr_t;
// async global->LDS, 16B per lane, dest = uniform base + lane*16
#define GLL16(g, l) __builtin_amdgcn_global_load_lds((gptr_t)(g), (sptr_t)(l), 16, 0, 0)

__device__ __forceinline__ ushort f2b(float f) {
    __hip_bfloat16 h = __float2bfloat16(f);   // RNE
    return *reinterpret_cast<ushort*>(&h);
}
__device__ __forceinline__ float b2f(ushort u) {
    return __uint_as_float(((unsigned)u) << 16);   // exact
}

// ---------------------------------------------------------------------------
// prep: cast weights to bf16 (Wqkv = [wq;wk;wv] rows, (768,256)), pack biases
// ---------------------------------------------------------------------------
__global__ __launch_bounds__(256) void prep_w(
    const float* __restrict__ wq, const float* __restrict__ wk,
    const float* __restrict__ wv, const float* __restrict__ wo,
    const float* __restrict__ bq, const float* __restrict__ bk,
    const float* __restrict__ bv,
    ushort* __restrict__ Wqkv, ushort* __restrict__ Wo, float* __restrict__ Bqkv)
{
    const int i = blockIdx.x * 256 + threadIdx.x;   // grid 256 -> i < 65536
    Wqkv[i]           = f2b(wq[i]);
    Wqkv[65536 + i]   = f2b(wk[i]);
    Wqkv[131072 + i]  = f2b(wv[i]);
    Wo[i]             = f2b(wo[i]);
    if (i < 256) { Bqkv[i] = bq[i]; Bqkv[256 + i] = bk[i]; Bqkv[512 + i] = bv[i]; }
}

// ---------------------------------------------------------------------------
// transpose: x (256, 32768) fp32 -> Xt (32768, 256) bf16
// ---------------------------------------------------------------------------
__global__ __launch_bounds__(256) void transpose_x(
    const float* __restrict__ x, ushort* __restrict__ Xt)
{
    __shared__ float ts[64][65];
    const int p0 = blockIdx.x * 64, c0 = blockIdx.y * 64;
    const int t = threadIdx.x;
    const int pl = t & 63, cl = t >> 6;
    #pragma unroll
    for (int i = 0; i < 16; ++i)
        ts[cl + 4 * i][pl] = x[(size_t)(c0 + cl + 4 * i) * P_TOT + p0 + pl];
    __syncthreads();
    const int pr = t >> 4, cc = (t & 15) * 4;
    #pragma unroll
    for (int i = 0; i < 4; ++i) {
        const int p = pr + 16 * i;
        ushort4 u;
        u.x = f2b(ts[cc + 0][p]); u.y = f2b(ts[cc + 1][p]);
        u.z = f2b(ts[cc + 2][p]); u.w = f2b(ts[cc + 3][p]);
        *(ushort4*)&Xt[(size_t)(p0 + p) * 256 + c0 + cc] = u;
    }
}

// ---------------------------------------------------------------------------
// GEMM1: QKV[p][o] = sum_c Xt[p][c] * Wqkv[o][c] + Bqkv[o]   (BT form)
// 1D grid, XCD-aware swizzle: the 6 n-tiles sharing one A(Xt)-tile get block
// ids equal mod 8 -> same XCD under round-robin dispatch -> A L2 reuse.
// ---------------------------------------------------------------------------
__global__ __launch_bounds__(256) void gemm_qkv(
    ushort* __restrict__ Xt, ushort* __restrict__ Wqkv,
    const float* __restrict__ Bqkv, ushort* __restrict__ QKV)
{
    __shared__ __align__(16) ushort As[128 * 32];
    __shared__ __align__(16) ushort Bs[128 * 32];

    const int ord   = blockIdx.x;                    // 0..1535
    const int n_idx = (ord >> 3) % 6;
    const int g     = (ord & 7) + 8 * (ord / 48);    // m-tile 0..255
    const int m0    = g * 128;                       // p
    const int n0    = n_idx * 128;                   // o

    const int t    = threadIdx.x;
    const int lane = t & 63;
    const int w    = t >> 6;
    const int wm   = (w & 1) * 64;
    const int wn   = (w >> 1) * 64;
    const int l16  = lane & 15;
    const int quad = lane >> 4;
    const int srow = lane >> 2;
    const int scol = (lane & 3) * 8;

    f32x4 acc[4][4] = {};

    for (int k0 = 0; k0 < 256; k0 += 32) {
        #pragma unroll
        for (int j = 0; j < 2; ++j) {
            const int i = w * 2 + j;
            GLL16(Xt   + (size_t)(m0 + i * 16 + srow) * 256 + k0 + scol, As + i * 512);
            GLL16(Wqkv + (size_t)(n0 + i * 16 + srow) * 256 + k0 + scol, Bs + i * 512);
        }
        __syncthreads();
        bf16x8 af[4], bfr[4];
        #pragma unroll
        for (int mi = 0; mi < 4; ++mi)
            af[mi] = *(const bf16x8*)(As + (wm + mi * 16 + l16) * 32 + quad * 8);
        #pragma unroll
        for (int ni = 0; ni < 4; ++ni)
            bfr[ni] = *(const bf16x8*)(Bs + (wn + ni * 16 + l16) * 32 + quad * 8);
        #pragma unroll
        for (int mi = 0; mi < 4; ++mi)
            #pragma unroll
            for (int ni = 0; ni < 4; ++ni)
                acc[mi][ni] = __builtin_amdgcn_mfma_f32_16x16x32_bf16(
                    af[mi], bfr[ni], acc[mi][ni], 0, 0, 0);
        __syncthreads();
    }

    #pragma unroll
    for (int ni = 0; ni < 4; ++ni) {
        const int og = n0 + wn + ni * 16 + l16;
        const float bias = Bqkv[og];
        #pragma unroll
        for (int mi = 0; mi < 4; ++mi)
            #pragma unroll
            for (int r = 0; r < 4; ++r) {
                const int pg = m0 + wm + mi * 16 + quad * 4 + r;
                QKV[(size_t)pg * O_QKV + og] = f2b(acc[mi][ni][r] + bias);
            }
    }
}

// ---------------------------------------------------------------------------
// attention: 8 pixels per 256-thread block; thread = (pixel, 8-channel group).
// __launch_bounds__(256,4): VGPR cap 128 so all 18 K/V 16B gathers stay in
// flight (at cap 48 the allocator serialized them -> latency-bound).
// ---------------------------------------------------------------------------
__global__ __launch_bounds__(256, 4) void attn_k(
    const float* __restrict__ grid, const ushort* __restrict__ QKV,
    ushort* __restrict__ Ab)
{
    __shared__ int   pk[8][9];
    __shared__ float sc[8][8][9];
    __shared__ float at[8][8][9];

    const int t  = threadIdx.x;
    const int p0 = blockIdx.x * 8;

    if (t < 72) {
        const int pix = t / 9, k = t - pix * 9;
        const int p = p0 + pix;
        const int h = p >> 8, w = p & 255;
        const int kh = k / 3, kw = k - kh * 3;
        const int gr = (h * 3 + kh) * 768 + (w * 3 + kw);
        const float gx = grid[gr * 2 + 0];
        const float gy = grid[gr * 2 + 1];
        int ix = (int)rintf((gx + 1.0f) * 0.5f * 255.0f);
        int iy = (int)rintf((gy + 1.0f) * 0.5f * 127.0f);
        ix = min(max(ix, 0), 255);
        iy = min(max(iy, 0), 127);
        pk[pix][k] = iy * 256 + ix;
    }
    __syncthreads();

    const int pix  = t >> 5;        // 0..7
    const int g    = t & 31;        // channel group
    const int sub  = g & 3;
    const int head = g >> 2;
    const int p    = p0 + pix;
    const int c8   = g * 8;

    const ushort8 q8 = *(const ushort8*)&QKV[(size_t)p * O_QKV + c8];

    ushort8 k8[9], v8[9];
    #pragma unroll
    for (int k = 0; k < 9; ++k) {
        const size_t base = (size_t)pk[pix][k] * O_QKV + c8;
        k8[k] = *(const ushort8*)&QKV[base + 256];
        v8[k] = *(const ushort8*)&QKV[base + 512];
    }

    #pragma unroll
    for (int k = 0; k < 9; ++k) {
        float d = 0.0f;
        #pragma unroll
        for (int i = 0; i < 8; ++i) d = fmaf(b2f(q8[i]), b2f(k8[k][i]), d);
        d += __shfl_xor(d, 1);
        d += __shfl_xor(d, 2);
        if (sub == 0) sc[pix][head][k] = d;
    }
    __syncthreads();

    if (t < 64) {
        const int px = t >> 3, hd = t & 7;
        const float scale = 0.17677669529663687f;  // 32^-0.5
        float s[9], m = -1e30f;
        #pragma unroll
        for (int k = 0; k < 9; ++k) { s[k] = sc[px][hd][k] * scale; m = fmaxf(m, s[k]); }
        float sum = 0.0f;
        #pragma unroll
        for (int k = 0; k < 9; ++k) { s[k] = expf(s[k] - m); sum += s[k]; }
        const float inv = 1.0f / sum;
        #pragma unroll
        for (int k = 0; k < 9; ++k) at[px][hd][k] = s[k] * inv;
    }
    __syncthreads();

    float o[8] = {};
    #pragma unroll
    for (int k = 0; k < 9; ++k) {
        const float a = at[pix][head][k];
        #pragma unroll
        for (int i = 0; i < 8; ++i) o[i] = fmaf(a, b2f(v8[k][i]), o[i]);
    }
    ushort8 r;
    #pragma unroll
    for (int i = 0; i < 8; ++i) r[i] = f2b(o[i]);
    *(ushort8*)&Ab[(size_t)p * 256 + c8] = r;
}

// ---------------------------------------------------------------------------
// GEMM2: y[o][p] = sum_c Wo[o][c] * Ab[p][c] + bo[o]
// XCD-aware swizzle: both o-tiles sharing one Ab-tile -> same XCD.
// ---------------------------------------------------------------------------
__global__ __launch_bounds__(256) void gemm_out(
    ushort* __restrict__ Wo, ushort* __restrict__ Ab,
    const float* __restrict__ bo, float* __restrict__ y)
{
    __shared__ __align__(16) ushort As[128 * 32];
    __shared__ __align__(16) ushort Bs[128 * 32];

    const int ord   = blockIdx.x;                  // 0..511
    const int o_idx = (ord >> 3) & 1;
    const int p_idx = (ord & 7) + 8 * (ord >> 4);
    const int m0    = o_idx * 128;                 // o
    const int n0    = p_idx * 128;                 // p

    const int t    = threadIdx.x;
    const int lane = t & 63;
    const int w    = t >> 6;
    const int wm   = (w & 1) * 64;
    const int wn   = (w >> 1) * 64;
    const int l16  = lane & 15;
    const int quad = lane >> 4;
    const int srow = lane >> 2;
    const int scol = (lane & 3) * 8;

    f32x4 acc[4][4] = {};

    for (int k0 = 0; k0 < 256; k0 += 32) {
        #pragma unroll
        for (int j = 0; j < 2; ++j) {
            const int i = w * 2 + j;
            GLL16(Wo + (size_t)(m0 + i * 16 + srow) * 256 + k0 + scol, As + i * 512);
            GLL16(Ab + (size_t)(n0 + i * 16 + srow) * 256 + k0 + scol, Bs + i * 512);
        }
        __syncthreads();
        bf16x8 af[4], bfr[4];
        #pragma unroll
        for (int mi = 0; mi < 4; ++mi)
            af[mi] = *(const bf16x8*)(As + (wm + mi * 16 + l16) * 32 + quad * 8);
        #pragma unroll
        for (int ni = 0; ni < 4; ++ni)
            bfr[ni] = *(const bf16x8*)(Bs + (wn + ni * 16 + l16) * 32 + quad * 8);
        #pragma unroll
        for (int mi = 0; mi < 4; ++mi)
            #pragma unroll
            for (int ni = 0; ni < 4; ++ni)
                acc[mi][ni] = __builtin_amdgcn_mfma_f32_16x16x32_bf16(
                    af[mi], bfr[ni], acc[mi][ni], 0, 0, 0);
        __syncthreads();
    }

    #pragma unroll
    for (int mi = 0; mi < 4; ++mi)
        #pragma unroll
        for (int r = 0; r < 4; ++r) {
            const int og = m0 + wm + mi * 16 + quad * 4 + r;
            const float bias = bo[og];
            #pragma unroll
            for (int ni = 0; ni < 4; ++ni) {
                const int pg = n0 + wn + ni * 16 + l16;
                y[(size_t)og * P_TOT + pg] = acc[mi][ni][r] + bias;
            }
        }
}

extern "C" void kernel_launch(void* const* d_in, const int* in_sizes, int n_in,
                              void* d_out, int out_size, void* d_ws, size_t ws_size,
                              hipStream_t stream) {
    const float* x    = (const float*)d_in[0];
    const float* grid = (const float*)d_in[1];
    const float* wq   = (const float*)d_in[2];
    const float* bq   = (const float*)d_in[3];
    const float* wk   = (const float*)d_in[4];
    const float* bk   = (const float*)d_in[5];
    const float* wv   = (const float*)d_in[6];
    const float* bv   = (const float*)d_in[7];
    const float* wo   = (const float*)d_in[8];
    const float* bo   = (const float*)d_in[9];
    float* y = (float*)d_out;

    ushort* Xt   = (ushort*)d_ws;                       // 16 MB
    ushort* QKV  = Xt  + (size_t)P_TOT * 256;           // 48 MB
    ushort* Ab   = QKV + (size_t)P_TOT * O_QKV;         // 16 MB
    ushort* Wqkv = Ab  + (size_t)P_TOT * 256;           // 384 KB
    ushort* Wo   = Wqkv + 768 * 256;                    // 128 KB
    float*  Bqkv = (float*)(Wo + 256 * 256);            // 3 KB

    prep_w<<<256, 256, 0, stream>>>(wq, wk, wv, wo, bq, bk, bv, Wqkv, Wo, Bqkv);
    transpose_x<<<dim3(P_TOT / 64, 4), 256, 0, stream>>>(x, Xt);
    gemm_qkv<<<1536, 256, 0, stream>>>(Xt, Wqkv, Bqkv, QKV);
    attn_k<<<P_TOT / 8, 256, 0, stream>>>(grid, QKV, Ab);
    gemm_out<<<512, 256, 0, stream>>>(Wo, Ab, bo, y);
}

// Round 5
// 179.199 us; speedup vs baseline: 1.0265x; 1.0265x over previous
//
#include <hip/hip_runtime.h>
#include <hip/hip_bf16.h>

#define P_TOT 32768   // H*W
#define O_QKV 768

using f32x4   = float  __attribute__((ext_vector_type(4)));
using bf16x8  = __bf16 __attribute__((ext_vector_type(8)));
using ushort8 = unsigned short __attribute__((ext_vector_type(8)));

typedef __attribute__((address_space(1))) void* gptr_t;
typedef __attribute__((address_space(3))) void* sptr_t;
// async global->LDS, 16B per lane, dest = uniform base + lane*16
#define GLL16(g, l) __builtin_amdgcn_global_load_lds((gptr_t)(g), (sptr_t)(l), 16, 0, 0)

__device__ __forceinline__ ushort f2b(float f) {
    __hip_bfloat16 h = __float2bfloat16(f);   // RNE
    return *reinterpret_cast<ushort*>(&h);
}
__device__ __forceinline__ float b2f(ushort u) {
    return __uint_as_float(((unsigned)u) << 16);   // exact
}

// ---------------------------------------------------------------------------
// prep: cast weights to bf16 (Wqkv = [wq;wk;wv] rows, (768,256)), pack biases
// ---------------------------------------------------------------------------
__global__ __launch_bounds__(256) void prep_w(
    const float* __restrict__ wq, const float* __restrict__ wk,
    const float* __restrict__ wv, const float* __restrict__ wo,
    const float* __restrict__ bq, const float* __restrict__ bk,
    const float* __restrict__ bv,
    ushort* __restrict__ Wqkv, ushort* __restrict__ Wo, float* __restrict__ Bqkv)
{
    const int i = blockIdx.x * 256 + threadIdx.x;   // grid 256 -> i < 65536
    Wqkv[i]           = f2b(wq[i]);
    Wqkv[65536 + i]   = f2b(wk[i]);
    Wqkv[131072 + i]  = f2b(wv[i]);
    Wo[i]             = f2b(wo[i]);
    if (i < 256) { Bqkv[i] = bq[i]; Bqkv[256 + i] = bk[i]; Bqkv[512 + i] = bv[i]; }
}

// ---------------------------------------------------------------------------
// transpose: x (256, 32768) fp32 -> Xt (32768, 256) bf16
// ---------------------------------------------------------------------------
__global__ __launch_bounds__(256) void transpose_x(
    const float* __restrict__ x, ushort* __restrict__ Xt)
{
    __shared__ float ts[64][65];
    const int p0 = blockIdx.x * 64, c0 = blockIdx.y * 64;
    const int t = threadIdx.x;
    const int pl = t & 63, cl = t >> 6;
    #pragma unroll
    for (int i = 0; i < 16; ++i)
        ts[cl + 4 * i][pl] = x[(size_t)(c0 + cl + 4 * i) * P_TOT + p0 + pl];
    __syncthreads();
    const int pr = t >> 4, cc = (t & 15) * 4;
    #pragma unroll
    for (int i = 0; i < 4; ++i) {
        const int p = pr + 16 * i;
        ushort4 u;
        u.x = f2b(ts[cc + 0][p]); u.y = f2b(ts[cc + 1][p]);
        u.z = f2b(ts[cc + 2][p]); u.w = f2b(ts[cc + 3][p]);
        *(ushort4*)&Xt[(size_t)(p0 + p) * 256 + c0 + cc] = u;
    }
}

// ---------------------------------------------------------------------------
// GEMM1: QKV[p][o] = sum_c Xt[p][c] * Wqkv[o][c] + Bqkv[o]   (BT form)
// BK=64: 4 K-iterations instead of 8 -> half the barrier drains.
// XCD swizzle: 6 n-tiles sharing an Xt-tile get ids equal mod 8 -> same XCD.
// ---------------------------------------------------------------------------
__global__ __launch_bounds__(256) void gemm_qkv(
    ushort* __restrict__ Xt, ushort* __restrict__ Wqkv,
    const float* __restrict__ Bqkv, ushort* __restrict__ QKV)
{
    __shared__ __align__(16) ushort As[128 * 64];   // 16 KB
    __shared__ __align__(16) ushort Bs[128 * 64];   // 16 KB

    const int ord   = blockIdx.x;                    // 0..1535
    const int n_idx = (ord >> 3) % 6;
    const int g     = (ord & 7) + 8 * (ord / 48);    // m-tile 0..255
    const int m0    = g * 128;                       // p
    const int n0    = n_idx * 128;                   // o

    const int t     = threadIdx.x;
    const int lane  = t & 63;
    const int w     = t >> 6;
    const int wm    = (w & 1) * 64;
    const int wn    = (w >> 1) * 64;
    const int l16   = lane & 15;
    const int quad  = lane >> 4;
    const int srow8 = lane >> 3;          // row within 8-row chunk
    const int scol8 = (lane & 7) * 8;     // col elements

    f32x4 acc[4][4] = {};

    for (int k0 = 0; k0 < 256; k0 += 64) {
        #pragma unroll
        for (int j = 0; j < 4; ++j) {
            const int i = w * 4 + j;      // 1KB chunk = 8 rows x 128B
            GLL16(Xt   + (size_t)(m0 + i * 8 + srow8) * 256 + k0 + scol8, As + i * 512);
            GLL16(Wqkv + (size_t)(n0 + i * 8 + srow8) * 256 + k0 + scol8, Bs + i * 512);
        }
        __syncthreads();
        #pragma unroll
        for (int s = 0; s < 2; ++s) {
            bf16x8 af[4], bfr[4];
            #pragma unroll
            for (int mi = 0; mi < 4; ++mi)
                af[mi] = *(const bf16x8*)(As + (wm + mi * 16 + l16) * 64 + s * 32 + quad * 8);
            #pragma unroll
            for (int ni = 0; ni < 4; ++ni)
                bfr[ni] = *(const bf16x8*)(Bs + (wn + ni * 16 + l16) * 64 + s * 32 + quad * 8);
            #pragma unroll
            for (int mi = 0; mi < 4; ++mi)
                #pragma unroll
                for (int ni = 0; ni < 4; ++ni)
                    acc[mi][ni] = __builtin_amdgcn_mfma_f32_16x16x32_bf16(
                        af[mi], bfr[ni], acc[mi][ni], 0, 0, 0);
        }
        __syncthreads();
    }

    #pragma unroll
    for (int ni = 0; ni < 4; ++ni) {
        const int og = n0 + wn + ni * 16 + l16;
        const float bias = Bqkv[og];
        #pragma unroll
        for (int mi = 0; mi < 4; ++mi)
            #pragma unroll
            for (int r = 0; r < 4; ++r) {
                const int pg = m0 + wm + mi * 16 + quad * 4 + r;
                QKV[(size_t)pg * O_QKV + og] = f2b(acc[mi][ni][r] + bias);
            }
    }
}

// ---------------------------------------------------------------------------
// attention: 8 pixels per 256-thread block; thread = (pixel, 8-channel group).
// sched_barrier(0) pins all 18 K/V 16B gathers BEFORE any use -> they stay
// in flight together (round-4 launch_bounds alone was defeated: VGPR stayed 48).
// ---------------------------------------------------------------------------
__global__ __launch_bounds__(256, 4) void attn_k(
    const float* __restrict__ grid, const ushort* __restrict__ QKV,
    ushort* __restrict__ Ab)
{
    __shared__ int   pk[8][9];
    __shared__ float sc[8][8][9];
    __shared__ float at[8][8][9];

    const int t  = threadIdx.x;
    const int p0 = blockIdx.x * 8;

    if (t < 72) {
        const int pix = t / 9, k = t - pix * 9;
        const int p = p0 + pix;
        const int h = p >> 8, w = p & 255;
        const int kh = k / 3, kw = k - kh * 3;
        const int gr = (h * 3 + kh) * 768 + (w * 3 + kw);
        const float gx = grid[gr * 2 + 0];
        const float gy = grid[gr * 2 + 1];
        int ix = (int)rintf((gx + 1.0f) * 0.5f * 255.0f);
        int iy = (int)rintf((gy + 1.0f) * 0.5f * 127.0f);
        ix = min(max(ix, 0), 255);
        iy = min(max(iy, 0), 127);
        pk[pix][k] = iy * 256 + ix;
    }
    __syncthreads();

    const int pix  = t >> 5;        // 0..7
    const int g    = t & 31;        // channel group
    const int sub  = g & 3;
    const int head = g >> 2;
    const int p    = p0 + pix;
    const int c8   = g * 8;

    const ushort8 q8 = *(const ushort8*)&QKV[(size_t)p * O_QKV + c8];

    ushort8 k8[9], v8[9];
    #pragma unroll
    for (int k = 0; k < 9; ++k) {
        const size_t base = (size_t)pk[pix][k] * O_QKV + c8;
        k8[k] = *(const ushort8*)&QKV[base + 256];
        v8[k] = *(const ushort8*)&QKV[base + 512];
    }
    __builtin_amdgcn_sched_barrier(0);   // do NOT sink these loads

    #pragma unroll
    for (int k = 0; k < 9; ++k) {
        float d = 0.0f;
        #pragma unroll
        for (int i = 0; i < 8; ++i) d = fmaf(b2f(q8[i]), b2f(k8[k][i]), d);
        d += __shfl_xor(d, 1);
        d += __shfl_xor(d, 2);
        if (sub == 0) sc[pix][head][k] = d;
    }
    __syncthreads();

    if (t < 64) {
        const int px = t >> 3, hd = t & 7;
        const float scale = 0.17677669529663687f;  // 32^-0.5
        float s[9], m = -1e30f;
        #pragma unroll
        for (int k = 0; k < 9; ++k) { s[k] = sc[px][hd][k] * scale; m = fmaxf(m, s[k]); }
        float sum = 0.0f;
        #pragma unroll
        for (int k = 0; k < 9; ++k) { s[k] = expf(s[k] - m); sum += s[k]; }
        const float inv = 1.0f / sum;
        #pragma unroll
        for (int k = 0; k < 9; ++k) at[px][hd][k] = s[k] * inv;
    }
    __syncthreads();

    float o[8] = {};
    #pragma unroll
    for (int k = 0; k < 9; ++k) {
        const float a = at[pix][head][k];
        #pragma unroll
        for (int i = 0; i < 8; ++i) o[i] = fmaf(a, b2f(v8[k][i]), o[i]);
    }
    ushort8 r;
    #pragma unroll
    for (int i = 0; i < 8; ++i) r[i] = f2b(o[i]);
    *(ushort8*)&Ab[(size_t)p * 256 + c8] = r;
}

// ---------------------------------------------------------------------------
// GEMM2: y[o][p] = sum_c Wo[o][c] * Ab[p][c] + bo[o].  BK=64.
// ---------------------------------------------------------------------------
__global__ __launch_bounds__(256) void gemm_out(
    ushort* __restrict__ Wo, ushort* __restrict__ Ab,
    const float* __restrict__ bo, float* __restrict__ y)
{
    __shared__ __align__(16) ushort As[128 * 64];
    __shared__ __align__(16) ushort Bs[128 * 64];

    const int ord   = blockIdx.x;                  // 0..511
    const int o_idx = (ord >> 3) & 1;
    const int p_idx = (ord & 7) + 8 * (ord >> 4);
    const int m0    = o_idx * 128;                 // o
    const int n0    = p_idx * 128;                 // p

    const int t     = threadIdx.x;
    const int lane  = t & 63;
    const int w     = t >> 6;
    const int wm    = (w & 1) * 64;
    const int wn    = (w >> 1) * 64;
    const int l16   = lane & 15;
    const int quad  = lane >> 4;
    const int srow8 = lane >> 3;
    const int scol8 = (lane & 7) * 8;

    f32x4 acc[4][4] = {};

    for (int k0 = 0; k0 < 256; k0 += 64) {
        #pragma unroll
        for (int j = 0; j < 4; ++j) {
            const int i = w * 4 + j;
            GLL16(Wo + (size_t)(m0 + i * 8 + srow8) * 256 + k0 + scol8, As + i * 512);
            GLL16(Ab + (size_t)(n0 + i * 8 + srow8) * 256 + k0 + scol8, Bs + i * 512);
        }
        __syncthreads();
        #pragma unroll
        for (int s = 0; s < 2; ++s) {
            bf16x8 af[4], bfr[4];
            #pragma unroll
            for (int mi = 0; mi < 4; ++mi)
                af[mi] = *(const bf16x8*)(As + (wm + mi * 16 + l16) * 64 + s * 32 + quad * 8);
            #pragma unroll
            for (int ni = 0; ni < 4; ++ni)
                bfr[ni] = *(const bf16x8*)(Bs + (wn + ni * 16 + l16) * 64 + s * 32 + quad * 8);
            #pragma unroll
            for (int mi = 0; mi < 4; ++mi)
                #pragma unroll
                for (int ni = 0; ni < 4; ++ni)
                    acc[mi][ni] = __builtin_amdgcn_mfma_f32_16x16x32_bf16(
                        af[mi], bfr[ni], acc[mi][ni], 0, 0, 0);
        }
        __syncthreads();
    }

    #pragma unroll
    for (int mi = 0; mi < 4; ++mi)
        #pragma unroll
        for (int r = 0; r < 4; ++r) {
            const int og = m0 + wm + mi * 16 + quad * 4 + r;
            const float bias = bo[og];
            #pragma unroll
            for (int ni = 0; ni < 4; ++ni) {
                const int pg = n0 + wn + ni * 16 + l16;
                y[(size_t)og * P_TOT + pg] = acc[mi][ni][r] + bias;
            }
        }
}

extern "C" void kernel_launch(void* const* d_in, const int* in_sizes, int n_in,
                              void* d_out, int out_size, void* d_ws, size_t ws_size,
                              hipStream_t stream) {
    const float* x    = (const float*)d_in[0];
    const float* grid = (const float*)d_in[1];
    const float* wq   = (const float*)d_in[2];
    const float* bq   = (const float*)d_in[3];
    const float* wk   = (const float*)d_in[4];
    const float* bk   = (const float*)d_in[5];
    const float* wv   = (const float*)d_in[6];
    const float* bv   = (const float*)d_in[7];
    const float* wo   = (const float*)d_in[8];
    const float* bo   = (const float*)d_in[9];
    float* y = (float*)d_out;

    ushort* Xt   = (ushort*)d_ws;                       // 16 MB
    ushort* QKV  = Xt  + (size_t)P_TOT * 256;           // 48 MB
    ushort* Ab   = QKV + (size_t)P_TOT * O_QKV;         // 16 MB
    ushort* Wqkv = Ab  + (size_t)P_TOT * 256;           // 384 KB
    ushort* Wo   = Wqkv + 768 * 256;                    // 128 KB
    float*  Bqkv = (float*)(Wo + 256 * 256);            // 3 KB

    prep_w<<<256, 256, 0, stream>>>(wq, wk, wv, wo, bq, bk, bv, Wqkv, Wo, Bqkv);
    transpose_x<<<dim3(P_TOT / 64, 4), 256, 0, stream>>>(x, Xt);
    gemm_qkv<<<1536, 256, 0, stream>>>(Xt, Wqkv, Bqkv, QKV);
    attn_k<<<P_TOT / 8, 256, 0, stream>>>(grid, QKV, Ab);
    gemm_out<<<512, 256, 0, stream>>>(Wo, Ab, bo, y);
}